// Round 5
// baseline (77.851 us; speedup 1.0000x reference)
//
#include <hip/hip_runtime.h>

typedef unsigned short u16;
typedef _Float16 f16x2 __attribute__((ext_vector_type(2)));
typedef _Float16 f16x8 __attribute__((ext_vector_type(8)));
typedef float    f32x4  __attribute__((ext_vector_type(4)));
typedef float    f32x16 __attribute__((ext_vector_type(16)));

// Fragment k-map convention (same in BOTH operand slots — proven r1-r4):
//   k_local(lane, j) = (lane>>5)*4 + (j&3) + 8*(j>>2),  j = 0..7
// D layout (m74/m101): col = lane&31 (N), row = (r&3)+8*(r>>2)+4*(lane>>5) (M)

union U4 { uint4 u; f16x8 h; u16 s[8]; };
union HU { f16x2 h2[4]; f16x8 h8; };

// ---------------------------------------------------------------------------
// Prep: ws layout (bytes):
//   [0,133120)        Bf  = W2flat (2080x32 f16) in B-fragment order
//   [133120,135168)   W1f normal  (col = nt*32 + l31)
//   [135168,137216)   W1fs row-swapped (col = nt*32 + (l31^4))  -> D rows m^4
//   [137216,137472)   b1p[h'][nt][r] = b1[nt*32 + (r&3)+8*(r>>2)+4h']  (f32)
// ---------------------------------------------------------------------------
__global__ void prep_kernel(const float* __restrict__ W1,
                            const float* __restrict__ b1,
                            const float* __restrict__ W2,
                            const float* __restrict__ b2,
                            u16* __restrict__ ws)
{
    int id = blockIdx.x * 256 + threadIdx.x;
    if (id < 8320) {                       // 130 ksteps * 64 lanes
        int k2 = id >> 6, l = id & 63;
        int h = l >> 5, col = l & 31;
        U4 o;
        #pragma unroll
        for (int g = 0; g < 2; ++g) {
            int base4 = k2 * 16 + g * 8 + h * 4;   // 4-aligned, no 32-straddle
            f32x4 v;
            if (base4 < 2048) {
                int k1 = base4 >> 5, j32 = base4 & 31;
                v = *(const f32x4*)&W2[k1 * 1024 + col * 32 + j32];
            } else {
                v = *(const f32x4*)&b2[col * 32 + (base4 - 2048)];
            }
            #pragma unroll
            for (int j = 0; j < 4; ++j)
                o.h[g * 4 + j] = (_Float16)v[j];
        }
        *(uint4*)(ws + id * 8) = o.u;
    } else if (id < 8576) {                // W1f (128) + W1fs (128)
        int idx = id - 8320;
        int sw  = idx >> 7;                // 0 = normal, 1 = swapped
        int nt = (idx >> 6) & 1, l = idx & 63;
        int h = l >> 5;
        int c31 = sw ? ((l & 31) ^ 4) : (l & 31);
        int col = nt * 32 + c31;
        U4 o;
        #pragma unroll
        for (int g = 0; g < 2; ++g)
            #pragma unroll
            for (int j = 0; j < 4; ++j) {
                int k = g * 8 + h * 4 + j;
                o.h[g * 4 + j] = (_Float16)W1[k * 64 + col];
            }
        *(uint4*)(ws + id * 8) = o.u;
    } else if (id < 8640) {                // b1p: 2h' * 2nt * 16r floats
        int idx = id - 8576;
        int hh = idx >> 5, nt = (idx >> 4) & 1, r = idx & 15;
        int row = (r & 3) + 8 * (r >> 2) + 4 * hh;
        ((float*)(ws + 68608))[idx] = b1[nt * 32 + row];
    }
}

__device__ __forceinline__ void stage16(const void* g, void* l) {
    __builtin_amdgcn_global_load_lds(
        (const __attribute__((address_space(1))) void*)g,
        (__attribute__((address_space(3))) void*)l, 16, 0, 0);
}

// ---------------------------------------------------------------------------
// Main kernel: 4 waves/block, 128 edges/wave (4 M-tiles) — halves per-edge
// LDS-pipe and front-end cost vs r4. hdn entirely in regs: layer-1 runs
// TWICE per tile (normal + row-swapped W1 fragment) so each lane gets both
// h-halves of hdn with zero cross-lane ops. K loop fully unrolled, B frags
// rotate-by-one prefetched from the 32 KB LDS double-buffer.
// ---------------------------------------------------------------------------
__global__ __launch_bounds__(256, 2) void edge_kernel(
    const float* __restrict__ h_w,
    const float* __restrict__ ef,
    const u16*  __restrict__ ws,
    float* __restrict__ out,
    int E)
{
    __shared__ alignas(16) u16 shm[16384];   // 32 KB
    const int tid  = threadIdx.x;
    const int lane = tid & 63;
    const int l31  = lane & 31;
    const int h    = lane >> 5;
    const int tileBase = (blockIdx.x * 4 + (tid >> 6)) * 128;
    const char* wsb = (const char*)ws;
    char*       shb = (char*)shm;

    // ---- stage chunk 0 (16 KB = k1 0..7) ----
    #pragma unroll
    for (int j = 0; j < 4; ++j)
        stage16(wsb + j * 4096 + tid * 16, shb + j * 4096 + tid * 16);

    // ---- h_w fragments (issued early; f16, kept in regs) ----
    f16x2 hwA[4][2][4];
    #pragma unroll
    for (int mt = 0; mt < 4; ++mt) {
        int e = tileBase + mt * 32 + l31;
        bool ok = e < E;
        f32x4 q0 = {}, q1 = {}, q2 = {}, q3 = {};
        if (ok) {
            const float* hp = h_w + (size_t)e * 32 + h * 4;
            q0 = *(const f32x4*)(hp);
            q1 = *(const f32x4*)(hp + 8);
            q2 = *(const f32x4*)(hp + 16);
            q3 = *(const f32x4*)(hp + 24);
        }
        hwA[mt][0][0] = f16x2{ (_Float16)q0[0], (_Float16)q0[1] };
        hwA[mt][0][1] = f16x2{ (_Float16)q0[2], (_Float16)q0[3] };
        hwA[mt][0][2] = f16x2{ (_Float16)q1[0], (_Float16)q1[1] };
        hwA[mt][0][3] = f16x2{ (_Float16)q1[2], (_Float16)q1[3] };
        hwA[mt][1][0] = f16x2{ (_Float16)q2[0], (_Float16)q2[1] };
        hwA[mt][1][1] = f16x2{ (_Float16)q2[2], (_Float16)q2[3] };
        hwA[mt][1][2] = f16x2{ (_Float16)q3[0], (_Float16)q3[1] };
        hwA[mt][1][3] = f16x2{ (_Float16)q3[2], (_Float16)q3[3] };
    }

    // ---- layer 1 (transposed, twice: normal + row-swapped) ----
    const uint4* W1f  = (const uint4*)(ws + 66560);
    const uint4* W1fs = (const uint4*)(ws + 67584);
    U4 wn0, wn1, wsw0, wsw1;
    wn0.u  = W1f[lane];   wn1.u  = W1f[64 + lane];
    wsw0.u = W1fs[lane];  wsw1.u = W1fs[64 + lane];
    const float* b1pf = (const float*)(ws + 68608);
    f32x4 bvo[2][4], bvf[2][4];
    #pragma unroll
    for (int nt = 0; nt < 2; ++nt)
        #pragma unroll
        for (int qr = 0; qr < 4; ++qr) {
            bvo[nt][qr] = *(const f32x4*)(b1pf + h * 32 + nt * 16 + qr * 4);
            bvf[nt][qr] = *(const f32x4*)(b1pf + (1 - h) * 32 + nt * 16 + qr * 4);
        }

    // Qh[hq==0] = QA, Qh[hq==1] = QB; pair p holds k1 = {8*(p>>1)+4hq+2*(p&1), +1}
    f16x2 QA[4][2][8], QB[4][2][8];
    #pragma unroll
    for (int mt = 0; mt < 4; ++mt) {
        int e = tileBase + mt * 32 + l31;
        bool ok = e < E;
        f32x4 g0 = {}, g1 = {};
        if (ok) {
            g0 = *(const f32x4*)&ef[e * 16 + h * 4];
            g1 = *(const f32x4*)&ef[e * 16 + 8 + h * 4];
        }
        U4 a;
        #pragma unroll
        for (int j = 0; j < 4; ++j) {
            a.h[j]     = (_Float16)g0[j];
            a.h[4 + j] = (_Float16)g1[j];
        }
        f32x16 cn0 = {}, cn1 = {}, cs0 = {}, cs1 = {};
        cn0 = __builtin_amdgcn_mfma_f32_32x32x16_f16(wn0.h,  a.h, cn0, 0, 0, 0);
        cn1 = __builtin_amdgcn_mfma_f32_32x32x16_f16(wn1.h,  a.h, cn1, 0, 0, 0);
        cs0 = __builtin_amdgcn_mfma_f32_32x32x16_f16(wsw0.h, a.h, cs0, 0, 0, 0);
        cs1 = __builtin_amdgcn_mfma_f32_32x32x16_f16(wsw1.h, a.h, cs1, 0, 0, 0);
        // reg r of cn: k1 = (r&3)+8*(r>>2)+4h (+32nt); of cs: same with 4(1-h)
        #pragma unroll
        for (int nt = 0; nt < 2; ++nt) {
            #pragma unroll
            for (int p = 0; p < 8; ++p) {
                const int r0 = 2 * p, r1 = 2 * p + 1;
                float n0 = fmaxf((nt ? cn1[r0] : cn0[r0]) + bvo[nt][r0 >> 2][r0 & 3], 0.f);
                float n1 = fmaxf((nt ? cn1[r1] : cn0[r1]) + bvo[nt][r1 >> 2][r1 & 3], 0.f);
                float s0 = fmaxf((nt ? cs1[r0] : cs0[r0]) + bvf[nt][r0 >> 2][r0 & 3], 0.f);
                float s1 = fmaxf((nt ? cs1[r1] : cs0[r1]) + bvf[nt][r1 >> 2][r1 & 3], 0.f);
                f16x2 pn = { (_Float16)n0, (_Float16)n1 };
                f16x2 ps = { (_Float16)s0, (_Float16)s1 };
                QA[mt][nt][p] = h ? ps : pn;   // h=0: normal is hq=0
                QB[mt][nt][p] = h ? pn : ps;   // h=1: normal is hq=1
            }
        }
    }

    f32x16 acc[4] = {};
    __syncthreads();   // chunk-0 stage drained

    // ---- K loop: 8 chunks x 8 k1, fully unrolled, rotate-by-one B regs ----
    #pragma unroll
    for (int c = 0; c < 8; ++c) {
        if (c < 7) {                       // stage chunk c+1 (16 KB)
            #pragma unroll
            for (int j = 0; j < 4; ++j)
                stage16(wsb + (c + 1) * 16384 + j * 4096 + tid * 16,
                        shb + ((c + 1) & 1) * 16384 + j * 4096 + tid * 16);
        } else {                           // tail (2 KB, ksteps 128-129) into buf0
            if (tid < 128)
                stage16(wsb + 131072 + tid * 16, shb + tid * 16);
        }
        const char* bB = shb + (c & 1) * 16384;
        U4 cur0, cur1, nxt0, nxt1;
        cur0.u = *(const uint4*)(bB + lane * 16);
        cur1.u = *(const uint4*)(bB + 1024 + lane * 16);
        #pragma unroll
        for (int qq = 0; qq < 8; ++qq) {
            if (qq < 7) {
                nxt0.u = *(const uint4*)(bB + (2 * qq + 2) * 1024 + lane * 16);
                nxt1.u = *(const uint4*)(bB + (2 * qq + 3) * 1024 + lane * 16);
            }
            const int k1   = c * 8 + qq;
            const int nt   = k1 >> 5;
            const int kk   = k1 & 31;
            const int hq   = (kk >> 2) & 1;
            const int p    = ((kk >> 3) << 1) + ((kk & 3) >> 1);
            const int half = kk & 1;
            #pragma unroll
            for (int mt = 0; mt < 4; ++mt) {
                _Float16 x = hq ? QB[mt][nt][p][half] : QA[mt][nt][p][half];
                f16x2 hh = { x, x };
                HU A;
                #pragma unroll
                for (int rr = 0; rr < 4; ++rr) A.h2[rr] = hh * hwA[mt][0][rr];
                acc[mt] = __builtin_amdgcn_mfma_f32_32x32x16_f16(A.h8, cur0.h, acc[mt], 0, 0, 0);
                #pragma unroll
                for (int rr = 0; rr < 4; ++rr) A.h2[rr] = hh * hwA[mt][1][rr];
                acc[mt] = __builtin_amdgcn_mfma_f32_32x32x16_f16(A.h8, cur1.h, acc[mt], 0, 0, 0);
            }
            if (qq < 7) { cur0 = nxt0; cur1 = nxt1; }
        }
        __syncthreads();
    }

    // ---- tail k1 = 64 (hdn == 1): A-frag = hwA directly, B in buf0 ----
    {
        U4 bf0, bf1;
        bf0.u = *(const uint4*)(shb + lane * 16);
        bf1.u = *(const uint4*)(shb + 1024 + lane * 16);
        #pragma unroll
        for (int mt = 0; mt < 4; ++mt) {
            HU A;
            #pragma unroll
            for (int rr = 0; rr < 4; ++rr) A.h2[rr] = hwA[mt][0][rr];
            acc[mt] = __builtin_amdgcn_mfma_f32_32x32x16_f16(A.h8, bf0.h, acc[mt], 0, 0, 0);
            #pragma unroll
            for (int rr = 0; rr < 4; ++rr) A.h2[rr] = hwA[mt][1][rr];
            acc[mt] = __builtin_amdgcn_mfma_f32_32x32x16_f16(A.h8, bf1.h, acc[mt], 0, 0, 0);
        }
    }

    // ---- store messages ----
    #pragma unroll
    for (int mt = 0; mt < 4; ++mt) {
        #pragma unroll
        for (int r = 0; r < 16; ++r) {
            int row = (r & 3) + 8 * (r >> 2) + 4 * h;
            int e = tileBase + mt * 32 + row;
            if (e < E) out[(size_t)e * 32 + l31] = acc[mt][r];
        }
    }
}

extern "C" void kernel_launch(void* const* d_in, const int* in_sizes, int n_in,
                              void* d_out, int out_size, void* d_ws, size_t ws_size,
                              hipStream_t stream)
{
    // inputs: 0=h_v (unused), 1=h_w, 2=edge_features, 3=W1, 4=b1, 5=W2, 6=b2
    const float* h_w = (const float*)d_in[1];
    const float* ef  = (const float*)d_in[2];
    const float* W1  = (const float*)d_in[3];
    const float* b1  = (const float*)d_in[4];
    const float* W2  = (const float*)d_in[5];
    const float* b2  = (const float*)d_in[6];
    float* out = (float*)d_out;
    const int E = in_sizes[1] / 32;
    u16* ws = (u16*)d_ws;   // needs 137,472 B

    prep_kernel<<<34, 256, 0, stream>>>(W1, b1, W2, b2, ws);

    const int blocks = (E + 511) / 512;
    edge_kernel<<<blocks, 256, 0, stream>>>(h_w, ef, ws, out, E);
}

// Round 6
// 63.507 us; speedup vs baseline: 1.2259x; 1.2259x over previous
//
#include <hip/hip_runtime.h>

typedef unsigned short u16;
typedef _Float16 f16x2 __attribute__((ext_vector_type(2)));
typedef _Float16 f16x8 __attribute__((ext_vector_type(8)));
typedef float    f32x4  __attribute__((ext_vector_type(4)));
typedef float    f32x16 __attribute__((ext_vector_type(16)));

// Fragment k-map convention (same in BOTH operand slots — proven r1-r5):
//   k_local(lane, j) = (lane>>5)*4 + (j&3) + 8*(j>>2),  j = 0..7
// D layout (m74/m101): col = lane&31 (N), row = (r&3)+8*(r>>2)+4*(lane>>5) (M)

union U4 { uint4 u; f16x8 h; u16 s[8]; };
union HU { f16x2 h2[4]; f16x8 h8; };

// ---------------------------------------------------------------------------
// Prep: ws layout (bytes):
//   [0,139264)        Bf = W2flat in B-fragment order, 136 ksteps (68 k1):
//                     ksteps 0..127 = W2, 128..129 = b2 rows, 130..135 = ZERO
//                     (zero-pad so the K loop is 17 uniform 8 KB chunks)
//   [139264,141312)   W1f normal   (col = nt*32 + l31)
//   [141312,143360)   W1fs swapped (col = nt*32 + (l31^4)) -> D rows m^4
//   [143360,143616)   b1p[h'][nt][r] = b1[nt*32 + (r&3)+8*(r>>2)+4h']  (f32)
// ---------------------------------------------------------------------------
__global__ void prep_kernel(const float* __restrict__ W1,
                            const float* __restrict__ b1,
                            const float* __restrict__ W2,
                            const float* __restrict__ b2,
                            u16* __restrict__ ws)
{
    int id = blockIdx.x * 256 + threadIdx.x;
    if (id < 8704) {                       // 136 ksteps * 64 lanes
        int k2 = id >> 6, l = id & 63;
        int h = l >> 5, col = l & 31;
        U4 o;
        if (k2 < 130) {
            #pragma unroll
            for (int g = 0; g < 2; ++g) {
                int base4 = k2 * 16 + g * 8 + h * 4;   // 4-aligned
                f32x4 v;
                if (base4 < 2048) {
                    int k1 = base4 >> 5, j32 = base4 & 31;
                    v = *(const f32x4*)&W2[k1 * 1024 + col * 32 + j32];
                } else {
                    v = *(const f32x4*)&b2[col * 32 + (base4 - 2048)];
                }
                #pragma unroll
                for (int j = 0; j < 4; ++j)
                    o.h[g * 4 + j] = (_Float16)v[j];
            }
        } else {
            o.u = uint4{0u, 0u, 0u, 0u};   // zero-pad k1 65..67
        }
        *(uint4*)(ws + id * 8) = o.u;
    } else if (id < 8960) {                // W1f (128) + W1fs (128)
        int idx = id - 8704;
        int sw  = idx >> 7;                // 0 = normal, 1 = swapped
        int nt = (idx >> 6) & 1, l = idx & 63;
        int h = l >> 5;
        int c31 = sw ? ((l & 31) ^ 4) : (l & 31);
        int col = nt * 32 + c31;
        U4 o;
        #pragma unroll
        for (int g = 0; g < 2; ++g)
            #pragma unroll
            for (int j = 0; j < 4; ++j) {
                int k = g * 8 + h * 4 + j;
                o.h[g * 4 + j] = (_Float16)W1[k * 64 + col];
            }
        *(uint4*)(ws + 69632 + idx * 8) = o.u;
    } else if (id < 9024) {                // b1p: 2h' * 2nt * 16r floats
        int idx = id - 8960;
        int hh = idx >> 5, nt = (idx >> 4) & 1, r = idx & 15;
        int row = (r & 3) + 8 * (r >> 2) + 4 * hh;
        ((float*)(ws + 71680))[idx] = b1[nt * 32 + row];
    }
}

__device__ __forceinline__ void stage16(const void* g, void* l) {
    __builtin_amdgcn_global_load_lds(
        (const __attribute__((address_space(1))) void*)g,
        (__attribute__((address_space(3))) void*)l, 16, 0, 0);
}

// ---------------------------------------------------------------------------
// Main kernel: 4 waves/block, 96 edges/wave (mt=3: largest spill-free tile;
// amortizes the per-wave 130 KB LDS B-read over 1.5x more edges than r4).
// B staged through a 3 x 8 KB LDS buffer rotation with COUNTED vmcnt (T4):
// stage(c+2) is issued before compute(c); the end-of-chunk wait is
// s_waitcnt vmcnt(2) — stage(c+2)'s loads stay in flight across the barrier
// (never drain to 0 in the main loop). hdn lives in registers via the
// dual-W1 transposed layer-1 (r5-validated). Chunk 16 (k1 64..67) is the
// bias row + zero-pad: A-frag = hwA directly, no Q lookup.
// ---------------------------------------------------------------------------
__global__ __launch_bounds__(256, 2) void edge_kernel(
    const float* __restrict__ h_w,
    const float* __restrict__ ef,
    const u16*  __restrict__ ws,
    float* __restrict__ out,
    int E)
{
    __shared__ alignas(16) u16 shm[12288];   // 24 KB = 3 x 8 KB
    const int tid  = threadIdx.x;
    const int lane = tid & 63;
    const int l31  = lane & 31;
    const int h    = lane >> 5;
    const int tileBase = (blockIdx.x * 4 + (tid >> 6)) * 96;
    const char* wsb = (const char*)ws;
    char*       shb = (char*)shm;

    // ---- stage chunks 0,1 (DMA runs under the whole prologue) ----
    stage16(wsb + tid * 16,         shb + tid * 16);
    stage16(wsb + 4096 + tid * 16,  shb + 4096 + tid * 16);
    stage16(wsb + 8192 + tid * 16,  shb + 8192 + tid * 16);
    stage16(wsb + 12288 + tid * 16, shb + 12288 + tid * 16);

    // ---- h_w fragments (f16, kept in regs) ----
    f16x2 hwA[3][2][4];
    #pragma unroll
    for (int mt = 0; mt < 3; ++mt) {
        int e = tileBase + mt * 32 + l31;
        bool ok = e < E;
        f32x4 q0 = {}, q1 = {}, q2 = {}, q3 = {};
        if (ok) {
            const float* hp = h_w + (size_t)e * 32 + h * 4;
            q0 = *(const f32x4*)(hp);
            q1 = *(const f32x4*)(hp + 8);
            q2 = *(const f32x4*)(hp + 16);
            q3 = *(const f32x4*)(hp + 24);
        }
        hwA[mt][0][0] = f16x2{ (_Float16)q0[0], (_Float16)q0[1] };
        hwA[mt][0][1] = f16x2{ (_Float16)q0[2], (_Float16)q0[3] };
        hwA[mt][0][2] = f16x2{ (_Float16)q1[0], (_Float16)q1[1] };
        hwA[mt][0][3] = f16x2{ (_Float16)q1[2], (_Float16)q1[3] };
        hwA[mt][1][0] = f16x2{ (_Float16)q2[0], (_Float16)q2[1] };
        hwA[mt][1][1] = f16x2{ (_Float16)q2[2], (_Float16)q2[3] };
        hwA[mt][1][2] = f16x2{ (_Float16)q3[0], (_Float16)q3[1] };
        hwA[mt][1][3] = f16x2{ (_Float16)q3[2], (_Float16)q3[3] };
    }

    // ---- layer 1 (transposed, dual-W1: normal + row-swapped) ----
    const uint4* W1f  = (const uint4*)(ws + 69632);
    const uint4* W1fs = (const uint4*)(ws + 70656);
    U4 wn0, wn1, wsw0, wsw1;
    wn0.u  = W1f[lane];   wn1.u  = W1f[64 + lane];
    wsw0.u = W1fs[lane];  wsw1.u = W1fs[64 + lane];
    const float* b1pf = (const float*)(ws + 71680);
    f32x4 bvo[2][4], bvf[2][4];
    #pragma unroll
    for (int nt = 0; nt < 2; ++nt)
        #pragma unroll
        for (int qr = 0; qr < 4; ++qr) {
            bvo[nt][qr] = *(const f32x4*)(b1pf + h * 32 + nt * 16 + qr * 4);
            bvf[nt][qr] = *(const f32x4*)(b1pf + (1 - h) * 32 + nt * 16 + qr * 4);
        }

    // QA = hq0, QB = hq1; k1 = 32nt + 8*(p>>1) + 4hq + 2*(p&1) + half
    f16x2 QA[3][2][8], QB[3][2][8];     // 96 VGPRs
    #pragma unroll
    for (int mt = 0; mt < 3; ++mt) {
        int e = tileBase + mt * 32 + l31;
        bool ok = e < E;
        f32x4 g0 = {}, g1 = {};
        if (ok) {
            g0 = *(const f32x4*)&ef[e * 16 + h * 4];
            g1 = *(const f32x4*)&ef[e * 16 + 8 + h * 4];
        }
        U4 a;
        #pragma unroll
        for (int j = 0; j < 4; ++j) {
            a.h[j]     = (_Float16)g0[j];
            a.h[4 + j] = (_Float16)g1[j];
        }
        f32x16 cn0 = {}, cn1 = {}, cs0 = {}, cs1 = {};
        cn0 = __builtin_amdgcn_mfma_f32_32x32x16_f16(wn0.h,  a.h, cn0, 0, 0, 0);
        cn1 = __builtin_amdgcn_mfma_f32_32x32x16_f16(wn1.h,  a.h, cn1, 0, 0, 0);
        cs0 = __builtin_amdgcn_mfma_f32_32x32x16_f16(wsw0.h, a.h, cs0, 0, 0, 0);
        cs1 = __builtin_amdgcn_mfma_f32_32x32x16_f16(wsw1.h, a.h, cs1, 0, 0, 0);
        #pragma unroll
        for (int nt = 0; nt < 2; ++nt) {
            #pragma unroll
            for (int p = 0; p < 8; ++p) {
                const int r0 = 2 * p, r1 = 2 * p + 1;
                float n0 = fmaxf((nt ? cn1[r0] : cn0[r0]) + bvo[nt][r0 >> 2][r0 & 3], 0.f);
                float n1 = fmaxf((nt ? cn1[r1] : cn0[r1]) + bvo[nt][r1 >> 2][r1 & 3], 0.f);
                float s0 = fmaxf((nt ? cs1[r0] : cs0[r0]) + bvf[nt][r0 >> 2][r0 & 3], 0.f);
                float s1 = fmaxf((nt ? cs1[r1] : cs0[r1]) + bvf[nt][r1 >> 2][r1 & 3], 0.f);
                f16x2 pn = { (_Float16)n0, (_Float16)n1 };
                f16x2 ps = { (_Float16)s0, (_Float16)s1 };
                QA[mt][nt][p] = h ? ps : pn;
                QB[mt][nt][p] = h ? pn : ps;
            }
        }
    }

    f32x16 acc[3] = {};

    // all except the 2 newest loads (stage-1's) drained -> buf0 ready
    asm volatile("s_waitcnt vmcnt(2)" ::: "memory");
    __builtin_amdgcn_s_barrier();

    // ---- K loop: 17 uniform chunks x 4 k1, counted-vmcnt 3-buffer ----
    #pragma unroll
    for (int c = 0; c < 17; ++c) {
        if (c + 2 <= 16) {                 // stage chunk c+2 -> buf (c+2)%3
            stage16(wsb + (c + 2) * 8192 + tid * 16,
                    shb + ((c + 2) % 3) * 8192 + tid * 16);
            stage16(wsb + (c + 2) * 8192 + 4096 + tid * 16,
                    shb + ((c + 2) % 3) * 8192 + 4096 + tid * 16);
        }
        const char* bB = shb + (c % 3) * 8192;
        #pragma unroll
        for (int q = 0; q < 4; ++q) {
            const int k1 = c * 4 + q;
            U4 bf0, bf1;
            bf0.u = *(const uint4*)(bB + (2 * q) * 1024 + lane * 16);
            bf1.u = *(const uint4*)(bB + (2 * q + 1) * 1024 + lane * 16);
            if (k1 < 64) {
                const int nt   = k1 >> 5;
                const int kk   = k1 & 31;
                const int hq   = (kk >> 2) & 1;
                const int p    = ((kk >> 3) << 1) + ((kk & 3) >> 1);
                const int half = kk & 1;
                #pragma unroll
                for (int mt = 0; mt < 3; ++mt) {
                    _Float16 x = hq ? QB[mt][nt][p][half] : QA[mt][nt][p][half];
                    f16x2 hh = { x, x };
                    HU A;
                    #pragma unroll
                    for (int rr = 0; rr < 4; ++rr) A.h2[rr] = hh * hwA[mt][0][rr];
                    acc[mt] = __builtin_amdgcn_mfma_f32_32x32x16_f16(A.h8, bf0.h, acc[mt], 0, 0, 0);
                    #pragma unroll
                    for (int rr = 0; rr < 4; ++rr) A.h2[rr] = hh * hwA[mt][1][rr];
                    acc[mt] = __builtin_amdgcn_mfma_f32_32x32x16_f16(A.h8, bf1.h, acc[mt], 0, 0, 0);
                }
            } else {                        // k1 64 = bias row (hdn==1); 65-67 B==0
                #pragma unroll
                for (int mt = 0; mt < 3; ++mt) {
                    HU A;
                    #pragma unroll
                    for (int rr = 0; rr < 4; ++rr) A.h2[rr] = hwA[mt][0][rr];
                    acc[mt] = __builtin_amdgcn_mfma_f32_32x32x16_f16(A.h8, bf0.h, acc[mt], 0, 0, 0);
                    #pragma unroll
                    for (int rr = 0; rr < 4; ++rr) A.h2[rr] = hwA[mt][1][rr];
                    acc[mt] = __builtin_amdgcn_mfma_f32_32x32x16_f16(A.h8, bf1.h, acc[mt], 0, 0, 0);
                }
            }
        }
        if (c < 16) {                      // counted wait: never drain to 0
            if (c + 2 <= 16) { asm volatile("s_waitcnt vmcnt(2)" ::: "memory"); }
            else             { asm volatile("s_waitcnt vmcnt(0)" ::: "memory"); }
            __builtin_amdgcn_s_barrier();
        }
    }

    // ---- store messages ----
    #pragma unroll
    for (int mt = 0; mt < 3; ++mt) {
        #pragma unroll
        for (int r = 0; r < 16; ++r) {
            int row = (r & 3) + 8 * (r >> 2) + 4 * h;
            int e = tileBase + mt * 32 + row;
            if (e < E) out[(size_t)e * 32 + l31] = acc[mt][r];
        }
    }
}

extern "C" void kernel_launch(void* const* d_in, const int* in_sizes, int n_in,
                              void* d_out, int out_size, void* d_ws, size_t ws_size,
                              hipStream_t stream)
{
    // inputs: 0=h_v (unused), 1=h_w, 2=edge_features, 3=W1, 4=b1, 5=W2, 6=b2
    const float* h_w = (const float*)d_in[1];
    const float* ef  = (const float*)d_in[2];
    const float* W1  = (const float*)d_in[3];
    const float* b1  = (const float*)d_in[4];
    const float* W2  = (const float*)d_in[5];
    const float* b2  = (const float*)d_in[6];
    float* out = (float*)d_out;
    const int E = in_sizes[1] / 32;
    u16* ws = (u16*)d_ws;   // needs 143,616 B

    prep_kernel<<<36, 256, 0, stream>>>(W1, b1, W2, b2, ws);

    const int blocks = (E + 383) / 384;
    edge_kernel<<<blocks, 256, 0, stream>>>(h_w, ef, ws, out, E);
}